// Round 13
// baseline (373.236 us; speedup 1.0000x reference)
//
#include <hip/hip_runtime.h>

#define Tsz 512
#define Hsz 256

typedef __attribute__((ext_vector_type(8))) short short8;
typedef __attribute__((ext_vector_type(4))) short short4v;
typedef __attribute__((ext_vector_type(4))) float f32x4;

static __device__ __forceinline__ unsigned short f2bf(float f) {
    union { float f; unsigned int i; } v; v.f = f;
    unsigned int r = v.i + 0x7fffu + ((v.i >> 16) & 1u);   // RNE
    return (unsigned short)(r >> 16);
}
static __device__ __forceinline__ float bf2f(unsigned short u) {
    union { unsigned int i; float f; } v; v.i = ((unsigned int)u) << 16; return v.f;
}
static __device__ __forceinline__ short8 ld8f(const float* p) {
    const float4* q = (const float4*)p;
    float4 a = q[0], b = q[1];
    short8 v;
    v[0] = (short)f2bf(a.x); v[1] = (short)f2bf(a.y); v[2] = (short)f2bf(a.z); v[3] = (short)f2bf(a.w);
    v[4] = (short)f2bf(b.x); v[5] = (short)f2bf(b.y); v[6] = (short)f2bf(b.z); v[7] = (short)f2bf(b.w);
    return v;
}
static __device__ __forceinline__ float sigm(float z) {
    return __builtin_amdgcn_rcpf(1.f + __expf(-z));
}

// Pre-kernel: Wx f32 -> bf16 row-major in d_ws
__global__ __launch_bounds__(256) void cvt_wx(const float* __restrict__ Wxw,
                                              unsigned short* __restrict__ wxbf)
{
    int i = (blockIdx.x * 256 + threadIdx.x) * 4;
    float4 v = *(const float4*)(Wxw + i);
    short4v s4;
    s4[0] = (short)f2bf(v.x); s4[1] = (short)f2bf(v.y);
    s4[2] = (short)f2bf(v.z); s4[3] = (short)f2bf(v.w);
    *(short4v*)(wxbf + i) = s4;
}

// Fused MGU, 4 waves/block (256 thr), 1 block/CU (grid=256), wave w owns
// cols [w*64, w*64+64). 4-wave config gets the 256-VGPR budget (r3 counters):
// Wh[4][8] frags resident (128 regs), no spill. Epilogue: thread tid owns
// col tid exactly (nt=hi), all lanes active, coalesced h/out writes.
#define XP 264   // xs row stride (ushorts)
__global__ __launch_bounds__(256, 1) void mgu_fused(
    const float* __restrict__ x,   const unsigned short* __restrict__ wxbf,
    const float* __restrict__ Wxb, const float* __restrict__ Whw,
    const float* __restrict__ Whb, float* __restrict__ out)
{
    __shared__ __align__(16) unsigned short xs[2][16 * XP];   // bf16 x chunks
    __shared__ __align__(16) unsigned short gsb[2][16 * 256]; // bf16 gates
    __shared__ __align__(16) unsigned short hbuf[2][256];     // bf16 h double buffer

    const int tid  = threadIdx.x;
    const int b    = blockIdx.x;
    const int l    = tid & 63;
    const int w    = tid >> 6;       // 0..3
    const int lo16 = l & 15;
    const int hi   = l >> 4;

    // Wh B-frags resident: B[k][n]=Wh[n][k]; lane n=w*64+nt*16+lo16, k=ks*32+hi*8..+7
    short8 wfh[4][8];
    float  bh[4], bxv[4];
#pragma unroll
    for (int nt = 0; nt < 4; ++nt) {
        int n = w * 64 + nt * 16 + lo16;
        bh[nt]  = Whb[n];
        bxv[nt] = Wxb[n];
#pragma unroll
        for (int ks = 0; ks < 8; ++ks)
            wfh[nt][ks] = ld8f(Whw + (size_t)n * 256 + ks * 32 + hi * 8);
    }

    // gate B-frag stream base (bf16 row-major in d_ws); frag(nt,ks) at +nt*16*256+ks*32
    const unsigned short* gwb = wxbf + (size_t)(w * 64 + lo16) * 256 + hi * 8;

    const float* xrow = x   + (size_t)b * Tsz * Hsz;
    float*       orow = out + (size_t)b * Tsz * Hsz;

    // ---- prologue: stage x chunks 0,1 ----
#pragma unroll
    for (int i = 0; i < 8; ++i) {
        int idx = tid + i * 256;          // 0..2047
        int m   = idx >> 6;               // global row 0..31
        int j   = idx & 63;
        float4 v = *(const float4*)(xrow + (size_t)m * 256 + j * 4);
        short4v s4;
        s4[0] = (short)f2bf(v.x); s4[1] = (short)f2bf(v.y);
        s4[2] = (short)f2bf(v.z); s4[3] = (short)f2bf(v.w);
        *(short4v*)(&xs[m >> 4][(m & 15) * XP + j * 4]) = s4;
    }
    hbuf[0][tid] = 0;
    __syncthreads();

    // ---- gates chunk 0 (full pass: 32 MFMAs/wave, streamed B-frags) ----
    {
        f32x4 ag[4];
#pragma unroll
        for (int nt = 0; nt < 4; ++nt) { f32x4 z = {0.f, 0.f, 0.f, 0.f}; ag[nt] = z; }
#pragma unroll
        for (int ks = 0; ks < 8; ++ks) {
            short8 a = *(const short8*)(&xs[0][lo16 * XP + ks * 32 + hi * 8]);
#pragma unroll
            for (int nt = 0; nt < 4; ++nt) {
                short8 bf = *(const short8*)(gwb + nt * (16 * 256) + ks * 32);
                ag[nt] = __builtin_amdgcn_mfma_f32_16x16x32_bf16(a, bf, ag[nt], 0, 0, 0);
            }
        }
#pragma unroll
        for (int nt = 0; nt < 4; ++nt)
#pragma unroll
            for (int r = 0; r < 4; ++r)
                gsb[0][(hi * 4 + r) * 256 + w * 64 + nt * 16 + lo16] = f2bf(sigm(ag[nt][r] + bxv[nt]));
    }

    float  hreg = 0.f;
    float  g_carry = 0.f;
    float4 stgA, stgB;
    f32x4 accg[4];
#pragma unroll
    for (int nt = 0; nt < 4; ++nt) { f32x4 z = {0.f, 0.f, 0.f, 0.f}; accg[nt] = z; }
    short8 afg;

    for (int c = 0; c < 32; ++c) {
        unsigned short*       xs_rd = xs[(c & 1) ^ 1];   // chunk c+1 (drip source)
        unsigned short*       xs_wr = xs[c & 1];         // dead -> stage chunk c+2
        const unsigned short* gs_rd = gsb[c & 1];        // gates of chunk c
        unsigned short*       gs_wr = gsb[(c & 1) ^ 1];  // gates of chunk c+1
#pragma unroll
        for (int s = 0; s < 16; ++s) {
            const int pp = s & 1;               // hbuf parity (compile-time)
            const int t  = c * 16 + s;
            __syncthreads();                    // h[t-1], gates, staged x visible

            // gate for this step (prefetched one step ahead; gs stable in chunk)
            float g = (s == 0) ? bf2f(gs_rd[tid]) : g_carry;
            if (s < 15) g_carry = bf2f(gs_rd[(s + 1) * 256 + tid]);

            // drip Wx B-frags (2/step): issue L2 loads now, consume after h-MFMAs
            const int ksg = s >> 1;
            const int nt0 = (2 * s) & 3, nt1 = (2 * s + 1) & 3;
            short8 gb0 = *(const short8*)(gwb + nt0 * (16 * 256) + ksg * 32);
            short8 gb1 = *(const short8*)(gwb + nt1 * (16 * 256) + ksg * 32);

            // drip A-frag (even s)
            if ((s & 1) == 0)
                afg = *(const short8*)(&xs_rd[lo16 * XP + ksg * 32 + hi * 8]);

            // bulk staging of chunk c+2 (all threads; xs_wr dead this chunk)
            if (c < 30) {
                if (s == 0) {
                    stgA = *(const float4*)(xrow + (size_t)((c + 2) * 16 + (tid >> 6)) * 256 + (tid & 63) * 4);
                    stgB = *(const float4*)(xrow + (size_t)((c + 2) * 16 + 4 + (tid >> 6)) * 256 + (tid & 63) * 4);
                }
                if (s == 4) {
                    short4v s4;
                    s4[0] = (short)f2bf(stgA.x); s4[1] = (short)f2bf(stgA.y);
                    s4[2] = (short)f2bf(stgA.z); s4[3] = (short)f2bf(stgA.w);
                    *(short4v*)(&xs_wr[(tid >> 6) * XP + (tid & 63) * 4]) = s4;
                    s4[0] = (short)f2bf(stgB.x); s4[1] = (short)f2bf(stgB.y);
                    s4[2] = (short)f2bf(stgB.z); s4[3] = (short)f2bf(stgB.w);
                    *(short4v*)(&xs_wr[(4 + (tid >> 6)) * XP + (tid & 63) * 4]) = s4;
                }
                if (s == 8) {
                    stgA = *(const float4*)(xrow + (size_t)((c + 2) * 16 + 8 + (tid >> 6)) * 256 + (tid & 63) * 4);
                    stgB = *(const float4*)(xrow + (size_t)((c + 2) * 16 + 12 + (tid >> 6)) * 256 + (tid & 63) * 4);
                }
                if (s == 12) {
                    short4v s4;
                    s4[0] = (short)f2bf(stgA.x); s4[1] = (short)f2bf(stgA.y);
                    s4[2] = (short)f2bf(stgA.z); s4[3] = (short)f2bf(stgA.w);
                    *(short4v*)(&xs_wr[(8 + (tid >> 6)) * XP + (tid & 63) * 4]) = s4;
                    s4[0] = (short)f2bf(stgB.x); s4[1] = (short)f2bf(stgB.y);
                    s4[2] = (short)f2bf(stgB.z); s4[3] = (short)f2bf(stgB.w);
                    *(short4v*)(&xs_wr[(12 + (tid >> 6)) * XP + (tid & 63) * 4]) = s4;
                }
            }

            // h-matvec: 32 MFMAs/wave, 8 independent chains of 4 (split-K)
            f32x4 a0lo = {bh[0], 0.f, 0.f, 0.f}, a0hi = {0.f, 0.f, 0.f, 0.f};
            f32x4 a1lo = {bh[1], 0.f, 0.f, 0.f}, a1hi = {0.f, 0.f, 0.f, 0.f};
            f32x4 a2lo = {bh[2], 0.f, 0.f, 0.f}, a2hi = {0.f, 0.f, 0.f, 0.f};
            f32x4 a3lo = {bh[3], 0.f, 0.f, 0.f}, a3hi = {0.f, 0.f, 0.f, 0.f};
            {
                short8 afhA[4], afhB[4];
#pragma unroll
                for (int ks = 0; ks < 4; ++ks)
                    afhA[ks] = *(const short8*)(const void*)(&hbuf[pp][ks * 32 + hi * 8]);
#pragma unroll
                for (int ks = 0; ks < 4; ++ks)
                    afhB[ks] = *(const short8*)(const void*)(&hbuf[pp][(ks + 4) * 32 + hi * 8]);
#pragma unroll
                for (int ks = 0; ks < 4; ++ks) {
                    a0lo = __builtin_amdgcn_mfma_f32_16x16x32_bf16(afhA[ks], wfh[0][ks],     a0lo, 0, 0, 0);
                    a1lo = __builtin_amdgcn_mfma_f32_16x16x32_bf16(afhA[ks], wfh[1][ks],     a1lo, 0, 0, 0);
                    a2lo = __builtin_amdgcn_mfma_f32_16x16x32_bf16(afhA[ks], wfh[2][ks],     a2lo, 0, 0, 0);
                    a3lo = __builtin_amdgcn_mfma_f32_16x16x32_bf16(afhA[ks], wfh[3][ks],     a3lo, 0, 0, 0);
                    a0hi = __builtin_amdgcn_mfma_f32_16x16x32_bf16(afhB[ks], wfh[0][ks + 4], a0hi, 0, 0, 0);
                    a1hi = __builtin_amdgcn_mfma_f32_16x16x32_bf16(afhB[ks], wfh[1][ks + 4], a1hi, 0, 0, 0);
                    a2hi = __builtin_amdgcn_mfma_f32_16x16x32_bf16(afhB[ks], wfh[2][ks + 4], a2hi, 0, 0, 0);
                    a3hi = __builtin_amdgcn_mfma_f32_16x16x32_bf16(afhB[ks], wfh[3][ks + 4], a3hi, 0, 0, 0);
                }
            }

            // gate drip: 2 MFMAs/step (compile-time nt indices)
            accg[nt0] = __builtin_amdgcn_mfma_f32_16x16x32_bf16(afg, gb0, accg[nt0], 0, 0, 0);
            accg[nt1] = __builtin_amdgcn_mfma_f32_16x16x32_bf16(afg, gb1, accg[nt1], 0, 0, 0);

            // epilogue: nt=hi -> thread tid owns col tid; all 256 lanes active
            float zz = (hi == 0) ? (a0lo[0] + a0hi[0]) : (hi == 1) ? (a1lo[0] + a1hi[0])
                     : (hi == 2) ? (a2lo[0] + a2hi[0]) : (a3lo[0] + a3hi[0]);
            zz = fminf(fmaxf(zz, -15.f), 15.f);
            float ex = __expf(2.f * zz);
            float th = (ex - 1.f) * __builtin_amdgcn_rcpf(ex + 1.f);
            float hn = th + g * (hreg - th);
            hreg = hn;
            hbuf[pp ^ 1][tid] = f2bf(hn);
            orow[(size_t)t * 256 + tid] = hn;

            if (s == 15) {   // finish gates chunk c+1
#pragma unroll
                for (int nt = 0; nt < 4; ++nt) {
#pragma unroll
                    for (int r = 0; r < 4; ++r)
                        gs_wr[(hi * 4 + r) * 256 + w * 64 + nt * 16 + lo16]
                            = f2bf(sigm(accg[nt][r] + bxv[nt]));
                    f32x4 z = {0.f, 0.f, 0.f, 0.f}; accg[nt] = z;
                }
            }
        }
    }
}

extern "C" void kernel_launch(void* const* d_in, const int* in_sizes, int n_in,
                              void* d_out, int out_size, void* d_ws, size_t ws_size,
                              hipStream_t stream) {
    const float* x   = (const float*)d_in[0];
    const float* Wxw = (const float*)d_in[1];
    const float* Wxb = (const float*)d_in[2];
    const float* Whw = (const float*)d_in[3];
    const float* Whb = (const float*)d_in[4];
    unsigned short* wxbf = (unsigned short*)d_ws;   // 128 KiB bf16 Wx

    cvt_wx<<<dim3(64), dim3(256), 0, stream>>>(Wxw, wxbf);
    mgu_fused<<<dim3(256), dim3(256), 0, stream>>>(x, wxbf, Wxb, Whw, Whb, (float*)d_out);
}

// Round 14
// 249.541 us; speedup vs baseline: 1.4957x; 1.4957x over previous
//
#include <hip/hip_runtime.h>

#define Tsz 512
#define Hsz 256

typedef __attribute__((ext_vector_type(8))) short short8;
typedef __attribute__((ext_vector_type(4))) short short4v;
typedef __attribute__((ext_vector_type(4))) float f32x4;

static __device__ __forceinline__ unsigned short f2bf(float f) {
    union { float f; unsigned int i; } v; v.f = f;
    unsigned int r = v.i + 0x7fffu + ((v.i >> 16) & 1u);   // RNE
    return (unsigned short)(r >> 16);
}
static __device__ __forceinline__ float bf2f(unsigned short u) {
    union { unsigned int i; float f; } v; v.i = ((unsigned int)u) << 16; return v.f;
}
static __device__ __forceinline__ short8 ld8f(const float* p) {
    const float4* q = (const float4*)p;
    float4 a = q[0], b = q[1];
    short8 v;
    v[0] = (short)f2bf(a.x); v[1] = (short)f2bf(a.y); v[2] = (short)f2bf(a.z); v[3] = (short)f2bf(a.w);
    v[4] = (short)f2bf(b.x); v[5] = (short)f2bf(b.y); v[6] = (short)f2bf(b.z); v[7] = (short)f2bf(b.w);
    return v;
}
static __device__ __forceinline__ float sigm(float z) {
    return __builtin_amdgcn_rcpf(1.f + __expf(-z));
}

// Pre-kernel: Wx f32 -> bf16 row-major in d_ws
__global__ __launch_bounds__(256) void cvt_wx(const float* __restrict__ Wxw,
                                              unsigned short* __restrict__ wxbf)
{
    int i = (blockIdx.x * 256 + threadIdx.x) * 4;
    float4 v = *(const float4*)(Wxw + i);
    short4v s4;
    s4[0] = (short)f2bf(v.x); s4[1] = (short)f2bf(v.y);
    s4[2] = (short)f2bf(v.z); s4[3] = (short)f2bf(v.w);
    *(short4v*)(wxbf + i) = s4;
}

// Fused MGU, 8 waves/block, 1 block/CU (r12 base). New in r14:
//  - ks-rotation: wave w consumes k-slices (w, w+1, ..) with pre-rotated Wh
//    frags; slice w = wave's OWN just-written h cols -> A-frag[0] is ds_read
//    PRE-barrier (same-wave RAW, compiler-ordered). Post-barrier path loses
//    the first ds_read latency.
//  - hbuf mirrored [2][512] (h duplicated at +256): rotated reads use
//    compile-time immediates, no wrap.
//  - zero-C acc trick: first MFMA of each chain takes persistent Z4 as C;
//    bias folded into epilogue (kills ~32 v_mov/step/wave).
#define XP 264   // xs row stride (ushorts)
__global__ __launch_bounds__(512, 2) void mgu_fused(
    const float* __restrict__ x,   const unsigned short* __restrict__ wxbf,
    const float* __restrict__ Wxb, const float* __restrict__ Whw,
    const float* __restrict__ Whb, float* __restrict__ out)
{
    __shared__ __align__(16) unsigned short xs[2][16 * XP];   // bf16 x chunks
    __shared__ __align__(16) unsigned short gsb[2][16 * 256]; // bf16 gates
    __shared__ __align__(16) unsigned short hbuf[2][512];     // bf16 h, dbuf + MIRRORED

    const int tid  = threadIdx.x;
    const int b    = blockIdx.x;
    const int l    = tid & 63;
    const int w    = tid >> 6;       // 0..7
    const int lo16 = l & 15;
    const int hi   = l >> 4;
    const int n_ep = w * 32 + (hi & 1) * 16 + lo16;   // epilogue col (hi<2 own)

    // Wh B-frags resident, ks-ROTATED: wfh[nt][kk] holds slice rks=(w+kk)&7
    short8 wfh[2][8];
    float  bh[2], bx[2];
#pragma unroll
    for (int nt = 0; nt < 2; ++nt) {
        int n = w * 32 + nt * 16 + lo16;
        bh[nt] = Whb[n];
        bx[nt] = Wxb[n];
#pragma unroll
        for (int kk = 0; kk < 8; ++kk) {
            int rks = (w + kk) & 7;
            wfh[nt][kk] = ld8f(Whw + (size_t)n * 256 + rks * 32 + hi * 8);
        }
    }
    const float bh_ep = (hi == 0) ? bh[0] : bh[1];

    // gate B-frag stream base (bf16 row-major in d_ws)
    const unsigned short* gwb = wxbf + (size_t)(w * 32 + lo16) * 256 + hi * 8;

    // rotated h-frag base byte offset within a parity copy (kk adds kk*64)
    const int   hbo = w * 64 + hi * 16;
    const char* hbb = (const char*)hbuf;

    const float* xrow = x   + (size_t)b * Tsz * Hsz;
    float*       optr = out + (size_t)b * Tsz * Hsz + n_ep;

    const int srow = tid >> 6;   // staging row 0..7
    const int sj   = tid & 63;

    // ---- prologue: stage x chunks 0,1; zero mirrored hbuf[0] ----
#pragma unroll
    for (int i = 0; i < 4; ++i) {
        int idx = tid + i * 512;
        int m   = idx >> 6;
        int j   = idx & 63;
        float4 v = *(const float4*)(xrow + (size_t)m * 256 + j * 4);
        short4v s4;
        s4[0] = (short)f2bf(v.x); s4[1] = (short)f2bf(v.y);
        s4[2] = (short)f2bf(v.z); s4[3] = (short)f2bf(v.w);
        *(short4v*)(&xs[m >> 4][(m & 15) * XP + j * 4]) = s4;
    }
    hbuf[0][tid] = 0;            // 512 threads cover both mirror halves
    __syncthreads();

    short8 afh0c = *(const short8*)(hbb + hbo);       // own slice, parity 0 (zeros)

    // ---- gates chunk 0 (full pass: 16 MFMAs/wave, streamed B-frags) ----
    {
        f32x4 ag0 = {0.f, 0.f, 0.f, 0.f}, ag1 = {0.f, 0.f, 0.f, 0.f};
#pragma unroll
        for (int ks = 0; ks < 8; ++ks) {
            short8 afg = *(const short8*)(&xs[0][lo16 * XP + ks * 32 + hi * 8]);
            short8 b0 = *(const short8*)(gwb + ks * 32);
            short8 b1 = *(const short8*)(gwb + 16 * 256 + ks * 32);
            ag0 = __builtin_amdgcn_mfma_f32_16x16x32_bf16(afg, b0, ag0, 0, 0, 0);
            ag1 = __builtin_amdgcn_mfma_f32_16x16x32_bf16(afg, b1, ag1, 0, 0, 0);
        }
#pragma unroll
        for (int r = 0; r < 4; ++r) {
            gsb[0][(hi * 4 + r) * 256 + w * 32 + lo16]      = f2bf(sigm(ag0[r] + bx[0]));
            gsb[0][(hi * 4 + r) * 256 + w * 32 + 16 + lo16] = f2bf(sigm(ag1[r] + bx[1]));
        }
    }

    float  hreg = 0.f;
    float  g_carry = 0.f;
    float4 stg;
    const f32x4 Z4 = {0.f, 0.f, 0.f, 0.f};   // persistent zero C for first MFMAs
    f32x4 accg[2];
    accg[0] = Z4; accg[1] = Z4;
    short8 afg;

    for (int c = 0; c < 32; ++c) {
        unsigned short*       xs_rd = xs[(c & 1) ^ 1];   // chunk c+1 (drip source)
        unsigned short*       xs_wr = xs[c & 1];         // dead -> stage chunk c+2
        const unsigned short* gs_rd = gsb[c & 1];
        unsigned short*       gs_wr = gsb[(c & 1) ^ 1];
#pragma unroll
        for (int s = 0; s < 16; ++s) {
            const int pp = s & 1;
            __syncthreads();                 // h[t-1], gates, staged x visible

            // gate (prefetched one step ahead; gsb stable within chunk)
            float g = (s == 0) ? bf2f(gs_rd[n_ep]) : g_carry;
            if (s < 15) g_carry = bf2f(gs_rd[(s + 1) * 256 + n_ep]);

            // gate B-frag: L2 load issued now, consumed after h-MFMAs
            short8 gbf = *(const short8*)(gwb + pp * (16 * 256) + (s >> 1) * 32);

            // drip A-frag (even s)
            if ((s & 1) == 0)
                afg = *(const short8*)(&xs_rd[lo16 * XP + (s >> 1) * 32 + hi * 8]);

            // bulk staging of chunk c+2 (all threads; xs_wr dead this chunk)
            if (c < 30) {
                if (s == 0)
                    stg = *(const float4*)(xrow + (size_t)((c + 2) * 16 + srow) * 256 + sj * 4);
                if (s == 4) {
                    short4v s4;
                    s4[0] = (short)f2bf(stg.x); s4[1] = (short)f2bf(stg.y);
                    s4[2] = (short)f2bf(stg.z); s4[3] = (short)f2bf(stg.w);
                    *(short4v*)(&xs_wr[srow * XP + sj * 4]) = s4;
                }
                if (s == 8)
                    stg = *(const float4*)(xrow + (size_t)((c + 2) * 16 + 8 + srow) * 256 + sj * 4);
                if (s == 12) {
                    short4v s4;
                    s4[0] = (short)f2bf(stg.x); s4[1] = (short)f2bf(stg.y);
                    s4[2] = (short)f2bf(stg.z); s4[3] = (short)f2bf(stg.w);
                    *(short4v*)(&xs_wr[(8 + srow) * XP + sj * 4]) = s4;
                }
            }

            // h-matvec, rotated: afh[0]=own slice (pre-read), rest post-barrier
            const char* hb = hbb + pp * 1024;
            short8 af1 = *(const short8*)(hb + hbo + 1 * 64);
            short8 af2 = *(const short8*)(hb + hbo + 2 * 64);
            short8 af3 = *(const short8*)(hb + hbo + 3 * 64);
            short8 af4 = *(const short8*)(hb + hbo + 4 * 64);
            short8 af5 = *(const short8*)(hb + hbo + 5 * 64);
            short8 af6 = *(const short8*)(hb + hbo + 6 * 64);
            short8 af7 = *(const short8*)(hb + hbo + 7 * 64);

            f32x4 a0lo = __builtin_amdgcn_mfma_f32_16x16x32_bf16(afh0c, wfh[0][0], Z4, 0, 0, 0);
            f32x4 a1lo = __builtin_amdgcn_mfma_f32_16x16x32_bf16(afh0c, wfh[1][0], Z4, 0, 0, 0);
            f32x4 a0hi = __builtin_amdgcn_mfma_f32_16x16x32_bf16(af4,   wfh[0][4], Z4, 0, 0, 0);
            f32x4 a1hi = __builtin_amdgcn_mfma_f32_16x16x32_bf16(af4,   wfh[1][4], Z4, 0, 0, 0);
            a0lo = __builtin_amdgcn_mfma_f32_16x16x32_bf16(af1, wfh[0][1], a0lo, 0, 0, 0);
            a1lo = __builtin_amdgcn_mfma_f32_16x16x32_bf16(af1, wfh[1][1], a1lo, 0, 0, 0);
            a0hi = __builtin_amdgcn_mfma_f32_16x16x32_bf16(af5, wfh[0][5], a0hi, 0, 0, 0);
            a1hi = __builtin_amdgcn_mfma_f32_16x16x32_bf16(af5, wfh[1][5], a1hi, 0, 0, 0);
            a0lo = __builtin_amdgcn_mfma_f32_16x16x32_bf16(af2, wfh[0][2], a0lo, 0, 0, 0);
            a1lo = __builtin_amdgcn_mfma_f32_16x16x32_bf16(af2, wfh[1][2], a1lo, 0, 0, 0);
            a0hi = __builtin_amdgcn_mfma_f32_16x16x32_bf16(af6, wfh[0][6], a0hi, 0, 0, 0);
            a1hi = __builtin_amdgcn_mfma_f32_16x16x32_bf16(af6, wfh[1][6], a1hi, 0, 0, 0);
            a0lo = __builtin_amdgcn_mfma_f32_16x16x32_bf16(af3, wfh[0][3], a0lo, 0, 0, 0);
            a1lo = __builtin_amdgcn_mfma_f32_16x16x32_bf16(af3, wfh[1][3], a1lo, 0, 0, 0);
            a0hi = __builtin_amdgcn_mfma_f32_16x16x32_bf16(af7, wfh[0][7], a0hi, 0, 0, 0);
            a1hi = __builtin_amdgcn_mfma_f32_16x16x32_bf16(af7, wfh[1][7], a1hi, 0, 0, 0);

            // gate drip: 1 MFMA/step
            accg[pp] = __builtin_amdgcn_mfma_f32_16x16x32_bf16(afg, gbf, accg[pp], 0, 0, 0);

            // epilogue (cols n_ep, hi<2 lanes)
            float zz = ((hi == 0) ? (a0lo[0] + a0hi[0]) : (a1lo[0] + a1hi[0])) + bh_ep;
            zz = fminf(fmaxf(zz, -15.f), 15.f);
            float ex = __expf(2.f * zz);
            float th = (ex - 1.f) * __builtin_amdgcn_rcpf(ex + 1.f);
            float hn = th + g * (hreg - th);
            if (hi < 2) {
                hreg = hn;
                unsigned short hb16 = f2bf(hn);
                hbuf[pp ^ 1][n_ep]       = hb16;   // primary
                hbuf[pp ^ 1][n_ep + 256] = hb16;   // mirror
                *optr = hn;
            }
            optr += 256;

            // pre-read own slice for NEXT step (parity pp^1): same-wave RAW,
            // ordered by lgkmcnt before the data is consumed after next barrier
            afh0c = *(const short8*)(hbb + (pp ^ 1) * 1024 + hbo);

            if (s == 15) {   // finish gates chunk c+1
#pragma unroll
                for (int r = 0; r < 4; ++r) {
                    gs_wr[(hi * 4 + r) * 256 + w * 32 + lo16]      = f2bf(sigm(accg[0][r] + bx[0]));
                    gs_wr[(hi * 4 + r) * 256 + w * 32 + 16 + lo16] = f2bf(sigm(accg[1][r] + bx[1]));
                }
                accg[0] = Z4; accg[1] = Z4;
            }
        }
    }
}

extern "C" void kernel_launch(void* const* d_in, const int* in_sizes, int n_in,
                              void* d_out, int out_size, void* d_ws, size_t ws_size,
                              hipStream_t stream) {
    const float* x   = (const float*)d_in[0];
    const float* Wxw = (const float*)d_in[1];
    const float* Wxb = (const float*)d_in[2];
    const float* Whw = (const float*)d_in[3];
    const float* Whb = (const float*)d_in[4];
    unsigned short* wxbf = (unsigned short*)d_ws;   // 128 KiB bf16 Wx

    cvt_wx<<<dim3(64), dim3(256), 0, stream>>>(Wxw, wxbf);
    mgu_fused<<<dim3(256), dim3(512), 0, stream>>>(x, wxbf, Wxb, Whw, Whb, (float*)d_out);
}

// Round 15
// 235.969 us; speedup vs baseline: 1.5817x; 1.0575x over previous
//
#include <hip/hip_runtime.h>

#define Tsz 512
#define Hsz 256

typedef __attribute__((ext_vector_type(8))) short short8;
typedef __attribute__((ext_vector_type(4))) short short4v;
typedef __attribute__((ext_vector_type(4))) float f32x4;

static __device__ __forceinline__ unsigned short f2bf(float f) {
    union { float f; unsigned int i; } v; v.f = f;
    unsigned int r = v.i + 0x7fffu + ((v.i >> 16) & 1u);   // RNE
    return (unsigned short)(r >> 16);
}
static __device__ __forceinline__ float bf2f(unsigned short u) {
    union { unsigned int i; float f; } v; v.i = ((unsigned int)u) << 16; return v.f;
}
static __device__ __forceinline__ short8 ld8f(const float* p) {
    const float4* q = (const float4*)p;
    float4 a = q[0], b = q[1];
    short8 v;
    v[0] = (short)f2bf(a.x); v[1] = (short)f2bf(a.y); v[2] = (short)f2bf(a.z); v[3] = (short)f2bf(a.w);
    v[4] = (short)f2bf(b.x); v[5] = (short)f2bf(b.y); v[6] = (short)f2bf(b.z); v[7] = (short)f2bf(b.w);
    return v;
}
static __device__ __forceinline__ float sigm(float z) {
    return __builtin_amdgcn_rcpf(1.f + __expf(-z));
}

// Pre-kernel: Wx f32 -> bf16 row-major in d_ws
__global__ __launch_bounds__(256) void cvt_wx(const float* __restrict__ Wxw,
                                              unsigned short* __restrict__ wxbf)
{
    int i = (blockIdx.x * 256 + threadIdx.x) * 4;
    float4 v = *(const float4*)(Wxw + i);
    short4v s4;
    s4[0] = (short)f2bf(v.x); s4[1] = (short)f2bf(v.y);
    s4[2] = (short)f2bf(v.z); s4[3] = (short)f2bf(v.w);
    *(short4v*)(wxbf + i) = s4;
}

// Fused MGU, r12 base (238us) + r15 micro-cuts:
//  - Z4 bias-fold: first MFMA of each chain uses persistent zero C; bias
//    added once in epilogue (removes 16 v_mov/step acc-init)
//  - static priority skew: odd waves at setprio(1) for the whole kernel ->
//    co-resident wave pair drifts out of phase; one wave's MFMA burst covers
//    the other's ds_read head / epilogue tail
//  - exp2f fold in tanh (v_exp_f32 is natively 2^x)
#define XP 264   // xs row stride (ushorts)
__global__ __launch_bounds__(512, 2) void mgu_fused(
    const float* __restrict__ x,   const unsigned short* __restrict__ wxbf,
    const float* __restrict__ Wxb, const float* __restrict__ Whw,
    const float* __restrict__ Whb, float* __restrict__ out)
{
    __shared__ __align__(16) unsigned short xs[2][16 * XP];   // bf16 x chunks
    __shared__ __align__(16) unsigned short gsb[2][16 * 256]; // bf16 gates
    __shared__ __align__(16) unsigned short hbuf[2][256];     // bf16 h double buffer

    const int tid  = threadIdx.x;
    const int b    = blockIdx.x;
    const int l    = tid & 63;
    const int w    = tid >> 6;       // 0..7
    const int lo16 = l & 15;
    const int hi   = l >> 4;
    const int n_ep = w * 32 + (hi & 1) * 16 + lo16;   // epilogue col (hi<2 own)

    // Wh B-frags resident: B[k][n]=Wh[n][k]; lane n=w*32+nt*16+lo16, k=ks*32+hi*8..+7
    short8 wfh[2][8];
    float  bh[2], bx[2];
#pragma unroll
    for (int nt = 0; nt < 2; ++nt) {
        int n = w * 32 + nt * 16 + lo16;
        bh[nt] = Whb[n];
        bx[nt] = Wxb[n];
#pragma unroll
        for (int ks = 0; ks < 8; ++ks)
            wfh[nt][ks] = ld8f(Whw + (size_t)n * 256 + ks * 32 + hi * 8);
    }
    const float bh_ep = (hi == 0) ? bh[0] : bh[1];

    // gate B-frag stream base (bf16 row-major in d_ws)
    const unsigned short* gwb = wxbf + (size_t)(w * 32 + lo16) * 256 + hi * 8;

    const float* xrow = x   + (size_t)b * Tsz * Hsz;
    float*       orow = out + (size_t)b * Tsz * Hsz;

    const int srow = tid >> 6;   // staging row 0..7
    const int sj   = tid & 63;

    // ---- prologue: stage x chunks 0,1 ----
#pragma unroll
    for (int i = 0; i < 4; ++i) {
        int idx = tid + i * 512;
        int m   = idx >> 6;
        int j   = idx & 63;
        float4 v = *(const float4*)(xrow + (size_t)m * 256 + j * 4);
        short4v s4;
        s4[0] = (short)f2bf(v.x); s4[1] = (short)f2bf(v.y);
        s4[2] = (short)f2bf(v.z); s4[3] = (short)f2bf(v.w);
        *(short4v*)(&xs[m >> 4][(m & 15) * XP + j * 4]) = s4;
    }
    if (tid < 256) hbuf[0][tid] = 0;
    __syncthreads();

    // ---- gates chunk 0 (full pass: 16 MFMAs/wave, streamed B-frags) ----
    {
        f32x4 ag0 = {0.f, 0.f, 0.f, 0.f}, ag1 = {0.f, 0.f, 0.f, 0.f};
#pragma unroll
        for (int ks = 0; ks < 8; ++ks) {
            short8 afg = *(const short8*)(&xs[0][lo16 * XP + ks * 32 + hi * 8]);
            short8 b0 = *(const short8*)(gwb + ks * 32);
            short8 b1 = *(const short8*)(gwb + 16 * 256 + ks * 32);
            ag0 = __builtin_amdgcn_mfma_f32_16x16x32_bf16(afg, b0, ag0, 0, 0, 0);
            ag1 = __builtin_amdgcn_mfma_f32_16x16x32_bf16(afg, b1, ag1, 0, 0, 0);
        }
#pragma unroll
        for (int r = 0; r < 4; ++r) {
            gsb[0][(hi * 4 + r) * 256 + w * 32 + lo16]      = f2bf(sigm(ag0[r] + bx[0]));
            gsb[0][(hi * 4 + r) * 256 + w * 32 + 16 + lo16] = f2bf(sigm(ag1[r] + bx[1]));
        }
    }

    // static priority skew: odd waves favored for the whole main loop
    if (w & 1) __builtin_amdgcn_s_setprio(1);

    float  hreg = 0.f;
    float  g_carry = 0.f;
    float4 stg;
    const f32x4 Z4 = {0.f, 0.f, 0.f, 0.f};
    f32x4 accg[2];
    accg[0] = Z4; accg[1] = Z4;
    short8 afg;

    for (int c = 0; c < 32; ++c) {
        unsigned short*       xs_rd = xs[(c & 1) ^ 1];   // chunk c+1 (drip source)
        unsigned short*       xs_wr = xs[c & 1];         // dead -> stage chunk c+2
        const unsigned short* gs_rd = gsb[c & 1];        // gates of chunk c (stable)
        unsigned short*       gs_wr = gsb[(c & 1) ^ 1];  // gates of chunk c+1
#pragma unroll
        for (int s = 0; s < 16; ++s) {
            const int pp = s & 1;               // hbuf parity (compile-time)
            const int t  = c * 16 + s;
            __syncthreads();                    // h[t-1], gates, staged x visible

            // gate for this step (prefetched one step ahead; gsb stable in chunk)
            float g = (s == 0) ? bf2f(gs_rd[n_ep]) : g_carry;
            if (s < 15) g_carry = bf2f(gs_rd[(s + 1) * 256 + n_ep]);

            // gate B-frag: L2 load issued now, consumed at drip MFMA later
            short8 gbf = *(const short8*)(gwb + pp * (16 * 256) + (s >> 1) * 32);

            // drip A-frag (even s)
            if ((s & 1) == 0)
                afg = *(const short8*)(&xs_rd[lo16 * XP + (s >> 1) * 32 + hi * 8]);

            // bulk staging of chunk c+2 (all threads; xs_wr dead this chunk)
            if (c < 30) {
                if (s == 0)
                    stg = *(const float4*)(xrow + (size_t)((c + 2) * 16 + srow) * 256 + sj * 4);
                if (s == 4) {
                    short4v s4;
                    s4[0] = (short)f2bf(stg.x); s4[1] = (short)f2bf(stg.y);
                    s4[2] = (short)f2bf(stg.z); s4[3] = (short)f2bf(stg.w);
                    *(short4v*)(&xs_wr[srow * XP + sj * 4]) = s4;
                }
                if (s == 8)
                    stg = *(const float4*)(xrow + (size_t)((c + 2) * 16 + 8 + srow) * 256 + sj * 4);
                if (s == 12) {
                    short4v s4;
                    s4[0] = (short)f2bf(stg.x); s4[1] = (short)f2bf(stg.y);
                    s4[2] = (short)f2bf(stg.z); s4[3] = (short)f2bf(stg.w);
                    *(short4v*)(&xs_wr[(8 + srow) * XP + sj * 4]) = s4;
                }
            }

            // h-matvec in two halves; first MFMA of each chain uses Z4 (bias folded out)
            f32x4 a0lo, a1lo, a0hi, a1hi;
            {
                short8 afh[4];
#pragma unroll
                for (int ks = 0; ks < 4; ++ks)
                    afh[ks] = *(const short8*)(const void*)(&hbuf[pp][ks * 32 + hi * 8]);
                a0lo = __builtin_amdgcn_mfma_f32_16x16x32_bf16(afh[0], wfh[0][0], Z4, 0, 0, 0);
                a1lo = __builtin_amdgcn_mfma_f32_16x16x32_bf16(afh[0], wfh[1][0], Z4, 0, 0, 0);
#pragma unroll
                for (int ks = 1; ks < 4; ++ks) {
                    a0lo = __builtin_amdgcn_mfma_f32_16x16x32_bf16(afh[ks], wfh[0][ks], a0lo, 0, 0, 0);
                    a1lo = __builtin_amdgcn_mfma_f32_16x16x32_bf16(afh[ks], wfh[1][ks], a1lo, 0, 0, 0);
                }
            }
            {
                short8 afh[4];
#pragma unroll
                for (int ks = 0; ks < 4; ++ks)
                    afh[ks] = *(const short8*)(const void*)(&hbuf[pp][(ks + 4) * 32 + hi * 8]);
                a0hi = __builtin_amdgcn_mfma_f32_16x16x32_bf16(afh[0], wfh[0][4], Z4, 0, 0, 0);
                a1hi = __builtin_amdgcn_mfma_f32_16x16x32_bf16(afh[0], wfh[1][4], Z4, 0, 0, 0);
#pragma unroll
                for (int ks = 1; ks < 4; ++ks) {
                    a0hi = __builtin_amdgcn_mfma_f32_16x16x32_bf16(afh[ks], wfh[0][ks + 4], a0hi, 0, 0, 0);
                    a1hi = __builtin_amdgcn_mfma_f32_16x16x32_bf16(afh[ks], wfh[1][ks + 4], a1hi, 0, 0, 0);
                }
            }

            // gate drip: 1 MFMA/step
            accg[pp] = __builtin_amdgcn_mfma_f32_16x16x32_bf16(afg, gbf, accg[pp], 0, 0, 0);

            // epilogue: col n_ep owned by hi<2 threads; bias added here (Z4 fold)
            float zz = ((hi == 0) ? (a0lo[0] + a0hi[0]) : (a1lo[0] + a1hi[0])) + bh_ep;
            zz = fminf(fmaxf(zz, -15.f), 15.f);
            float ex = exp2f(zz * 2.885390082f);    // e^{2z}
            float th = (ex - 1.f) * __builtin_amdgcn_rcpf(ex + 1.f);
            if (hi < 2) {
                float hn = th + g * (hreg - th);
                hreg = hn;
                hbuf[pp ^ 1][n_ep] = f2bf(hn);
                orow[(size_t)t * 256 + n_ep] = hn;
            }

            if (s == 15) {   // finish gates chunk c+1 (bf16 writes)
#pragma unroll
                for (int r = 0; r < 4; ++r) {
                    gs_wr[(hi * 4 + r) * 256 + w * 32 + lo16]      = f2bf(sigm(accg[0][r] + bx[0]));
                    gs_wr[(hi * 4 + r) * 256 + w * 32 + 16 + lo16] = f2bf(sigm(accg[1][r] + bx[1]));
                }
                accg[0] = Z4; accg[1] = Z4;
            }
        }
    }
}

extern "C" void kernel_launch(void* const* d_in, const int* in_sizes, int n_in,
                              void* d_out, int out_size, void* d_ws, size_t ws_size,
                              hipStream_t stream) {
    const float* x   = (const float*)d_in[0];
    const float* Wxw = (const float*)d_in[1];
    const float* Wxb = (const float*)d_in[2];
    const float* Whw = (const float*)d_in[3];
    const float* Whb = (const float*)d_in[4];
    unsigned short* wxbf = (unsigned short*)d_ws;   // 128 KiB bf16 Wx

    cvt_wx<<<dim3(64), dim3(256), 0, stream>>>(Wxw, wxbf);
    mgu_fused<<<dim3(256), dim3(512), 0, stream>>>(x, wxbf, Wxb, Whw, Whb, (float*)d_out);
}